// Round 4
// baseline (75.321 us; speedup 1.0000x reference)
//
#include <hip/hip_runtime.h>

#define D_CLAMP2 100.0f   // D_CLAMP^2 ; min(sqrt(x),10) == sqrt(min(x,100))
#define EPS_F    1e-4f
#define Z_F      10.0f
#define JCH      64       // j atoms per block (MUST be 64: staging uses >>6/&63)
#define ITILE    512      // i rows per block: 2 per lane (i and i+256)

typedef float v2f __attribute__((ext_vector_type(2)));
typedef float v4f __attribute__((ext_vector_type(4)));

#define F2(a,b,c) __builtin_elementwise_fma((a),(b),(c))
#define LO2(v) __builtin_shufflevector((v),(v),0,1)
#define HI2(v) __builtin_shufflevector((v),(v),2,3)

// ---------------------------------------------------------------------------
// ROUND 4. Regression over rounds 0-3 pins: dur = 40us poison fill (84% HBM,
// its own roofline) + ~23us harness resets + main ~9us + reduce ~2us. Only
// ISSUE COUNT moved dur (r2: -29% issues -> -2.7us); occupancy & SW pipeline
// were null (r3). So: amortize the per-group non-FMA issues across TWO
// i-rows per lane (ITILE=512, JCH=64 = best-measured config): the 6
// ds_read_b128 + loop overhead per 4-atom group now serve 2 frames
// (issues/pair 16 -> ~14.2), and per-lane ILP doubles.
// Predicted: dur 74.3 -> 72-73. If >=74: harness floor reached -> ROOFLINE.
// ---------------------------------------------------------------------------
__global__ __launch_bounds__(256, 2) void fape_main(
    const float* __restrict__ pred_rot,   // [B,N,3,3]
    const float* __restrict__ pred_trans, // [B,N,3]
    const float* __restrict__ pred_pos,   // [B,N,3]
    const float* __restrict__ true_rot,   // [B,N,3,3]
    const float* __restrict__ true_trans, // [B,N,3]
    const float* __restrict__ true_pos,   // [B,N,3]
    float* __restrict__ partial,          // [B, gridDim.x]
    int N, int jChunks)
{
    const int jc  = blockIdx.x % jChunks;   // 64-wide j slice
    const int fcb = blockIdx.x / jChunks;   // 512-wide i slice
    const int b   = blockIdx.y;
    const int j0  = jc * JCH;

    // ---- Stage j-slice into LDS, SoA: plane p in {a0,a1,a2,b0,b1,b2} ----
    __shared__ v4f spv[6][JCH / 4];         // 1.5 KB
    {
        float* spf = (float*)spv;
        const float* XPb = pred_pos + (size_t)b * N * 3;
        const float* XTb = true_pos + (size_t)b * N * 3;
        for (int idx = threadIdx.x; idx < 6 * JCH; idx += 256) {
            const int p  = idx >> 6;            // plane 0..5
            const int jj = idx & (JCH - 1);
            const int jA = j0 + jj;
            const int jv = jA < N ? jA : N - 1;
            spf[(p << 6) + jj] = (p < 3) ? XPb[3 * jv + p] : XTb[3 * jv + p - 3];
        }
    }

    // ---- Per-lane frame constants: TWO frames per lane ----
    const int iA = fcb * ITILE + threadIdx.x;
    const int iB = iA + 256;
    const float wFA = (iA < N) ? 1.0f : 0.0f;
    const float wFB = (iB < N) ? 1.0f : 0.0f;
    const int ivA = iA < N ? iA : N - 1;
    const int ivB = iB < N ? iB : N - 1;

    float rpA[9], rtA[9], cnA[3], rpB[9], rtB[9], cnB[3];
#define LOADFRAME(S, IV) do {                                                 \
        const size_t fi_ = (size_t)b * N + (IV);                              \
        const float* Rp_ = pred_rot + fi_ * 9;                                \
        const float* Rt_ = true_rot + fi_ * 9;                                \
        _Pragma("unroll")                                                     \
        for (int q = 0; q < 9; ++q) { rp##S[q] = Rp_[q]; rt##S[q] = Rt_[q]; } \
        const float* tp_ = pred_trans + fi_ * 3;                              \
        const float* tt_ = true_trans + fi_ * 3;                              \
        _Pragma("unroll")                                                     \
        for (int o = 0; o < 3; ++o)                                           \
            cn##S[o] = (rt##S[0+o]*tt_[0] + rt##S[3+o]*tt_[1] + rt##S[6+o]*tt_[2]) \
                     - (rp##S[0+o]*tp_[0] + rp##S[3+o]*tp_[1] + rp##S[6+o]*tp_[2]); \
    } while (0)
    LOADFRAME(A, ivA);
    LOADFRAME(B, ivB);
#undef LOADFRAME

    __syncthreads();

    float sA0 = 0.f, sA1 = 0.f, sA2 = 0.f, sA3 = 0.f;
    float sB0 = 0.f, sB1 = 0.f, sB2 = 0.f, sB3 = 0.f;

    if (j0 + JCH <= N) {
        // ---- Fast path: splat constants (scalar rp/rt die here) ----
        v2f PA[9], QA[9], PB[9], QB[9];
#pragma unroll
        for (int q = 0; q < 9; ++q) {
            PA[q] = (v2f){ rpA[q],  rpA[q]  };
            QA[q] = (v2f){ -rtA[q], -rtA[q] };
            PB[q] = (v2f){ rpB[q],  rpB[q]  };
            QB[q] = (v2f){ -rtB[q], -rtB[q] };
        }
        const v2f CA0 = { cnA[0], cnA[0] }, CA1 = { cnA[1], cnA[1] }, CA2 = { cnA[2], cnA[2] };
        const v2f CB0 = { cnB[0], cnB[0] }, CB1 = { cnB[1], cnB[1] }, CB2 = { cnB[2], cnB[2] };
        const v2f EPSV = { EPS_F, EPS_F };
        const v2f CLV  = { D_CLAMP2, D_CLAMP2 };

#define PAIR_BODY(P,Q,C0,C1,C2,A0,A1,A2,B0,B1,B2,SA,SB) do {                  \
        const v2f d0 = F2(P[0],(A0),F2(P[3],(A1),F2(P[6],(A2),                \
                       F2(Q[0],(B0),F2(Q[3],(B1),F2(Q[6],(B2),C0))))));       \
        const v2f d1 = F2(P[1],(A0),F2(P[4],(A1),F2(P[7],(A2),                \
                       F2(Q[1],(B0),F2(Q[4],(B1),F2(Q[7],(B2),C1))))));       \
        const v2f d2 = F2(P[2],(A0),F2(P[5],(A1),F2(P[8],(A2),                \
                       F2(Q[2],(B0),F2(Q[5],(B1),F2(Q[8],(B2),C2))))));       \
        const v2f sq = __builtin_elementwise_min(                             \
                           F2(d0,d0,F2(d1,d1,F2(d2,d2,EPSV))), CLV);          \
        SA += __builtin_amdgcn_sqrtf(sq.x);                                   \
        SB += __builtin_amdgcn_sqrtf(sq.y);                                   \
    } while (0)

#pragma unroll 2
        for (int g = 0; g < JCH / 4; ++g) {
            const v4f a0 = spv[0][g], a1 = spv[1][g], a2 = spv[2][g];
            const v4f y0 = spv[3][g], y1 = spv[4][g], y2 = spv[5][g];
            PAIR_BODY(PA,QA,CA0,CA1,CA2, LO2(a0),LO2(a1),LO2(a2), LO2(y0),LO2(y1),LO2(y2), sA0, sA1);
            PAIR_BODY(PA,QA,CA0,CA1,CA2, HI2(a0),HI2(a1),HI2(a2), HI2(y0),HI2(y1),HI2(y2), sA2, sA3);
            PAIR_BODY(PB,QB,CB0,CB1,CB2, LO2(a0),LO2(a1),LO2(a2), LO2(y0),LO2(y1),LO2(y2), sB0, sB1);
            PAIR_BODY(PB,QB,CB0,CB1,CB2, HI2(a0),HI2(a1),HI2(a2), HI2(y0),HI2(y1),HI2(y2), sB2, sB3);
        }
#undef PAIR_BODY
    } else {
        // ---- Masked tail (generic N; never taken for N=2048) ----
        const float* spf = (const float*)spv;
#define TAIL_BODY(S, ACC) do {                                                \
        const float d0 = fmaf(rp##S[0],a0,fmaf(rp##S[3],a1,fmaf(rp##S[6],a2,  \
                         fmaf(-rt##S[0],y0,fmaf(-rt##S[3],y1,fmaf(-rt##S[6],y2,cn##S[0])))))); \
        const float d1 = fmaf(rp##S[1],a0,fmaf(rp##S[4],a1,fmaf(rp##S[7],a2,  \
                         fmaf(-rt##S[1],y0,fmaf(-rt##S[4],y1,fmaf(-rt##S[7],y2,cn##S[1])))))); \
        const float d2 = fmaf(rp##S[2],a0,fmaf(rp##S[5],a1,fmaf(rp##S[8],a2,  \
                         fmaf(-rt##S[2],y0,fmaf(-rt##S[5],y1,fmaf(-rt##S[8],y2,cn##S[2])))))); \
        const float sq = fmaf(d0,d0,fmaf(d1,d1,fmaf(d2,d2,EPS_F)));           \
        ACC = fmaf(wj, __builtin_amdgcn_sqrtf(fminf(sq, D_CLAMP2)), ACC);     \
    } while (0)
        for (int jj = 0; jj < JCH; ++jj) {
            const float a0 = spf[jj],       a1 = spf[64 + jj],  a2 = spf[128 + jj];
            const float y0 = spf[192 + jj], y1 = spf[256 + jj], y2 = spf[320 + jj];
            const float wj = (j0 + jj < N) ? 1.0f : 0.0f;
            TAIL_BODY(A, sA0);
            TAIL_BODY(B, sB0);
        }
#undef TAIL_BODY
    }

    float sum = ((sA0 + sA1) + (sA2 + sA3)) * wFA
              + ((sB0 + sB1) + (sB2 + sB3)) * wFB;

    // Block reduction -> one plain store (no atomics).
#pragma unroll
    for (int off = 32; off > 0; off >>= 1)
        sum += __shfl_down(sum, off, 64);

    __shared__ float smem[4];
    const int lane = threadIdx.x & 63;
    const int wave = threadIdx.x >> 6;
    if (lane == 0) smem[wave] = sum;
    __syncthreads();
    if (threadIdx.x == 0)
        partial[(size_t)b * gridDim.x + blockIdx.x] = smem[0] + smem[1] + smem[2] + smem[3];
}

// One block per batch: deterministic tree-reduce of the partials, write out.
__global__ __launch_bounds__(256) void fape_reduce(
    const float* __restrict__ partial, float* __restrict__ out, int nPart, int N)
{
    const int b = blockIdx.x;
    float s = 0.0f;
    for (int t = threadIdx.x; t < nPart; t += 256)
        s += partial[(size_t)b * nPart + t];
#pragma unroll
    for (int off = 32; off > 0; off >>= 1)
        s += __shfl_down(s, off, 64);
    __shared__ float smem[4];
    const int lane = threadIdx.x & 63;
    const int wave = threadIdx.x >> 6;
    if (lane == 0) smem[wave] = s;
    __syncthreads();
    if (threadIdx.x == 0) {
        const float tot = smem[0] + smem[1] + smem[2] + smem[3];
        out[b] = tot / (Z_F * (float)N * (float)N);
    }
}

extern "C" void kernel_launch(void* const* d_in, const int* in_sizes, int n_in,
                              void* d_out, int out_size, void* d_ws, size_t ws_size,
                              hipStream_t stream) {
    const float* pred_rot   = (const float*)d_in[0];
    const float* pred_trans = (const float*)d_in[1];
    const float* pred_pos   = (const float*)d_in[2];
    const float* true_rot   = (const float*)d_in[3];
    const float* true_trans = (const float*)d_in[4];
    const float* true_pos   = (const float*)d_in[5];
    float* out = (float*)d_out;

    const int B = out_size;                  // 4
    const int BN = in_sizes[1] / 3;          // B*N
    const int N = BN / B;                    // 2048

    const int jChunks = (N + JCH - 1) / JCH;     // 32
    const int iChunks = (N + ITILE - 1) / ITILE; // 4
    const int nPart   = iChunks * jChunks;       // 128

    float* partial = (float*)d_ws;           // B*nPart*4 = 2 KB

    dim3 grid(nPart, B);                     // 512 blocks
    fape_main<<<grid, 256, 0, stream>>>(pred_rot, pred_trans, pred_pos,
                                        true_rot, true_trans, true_pos,
                                        partial, N, jChunks);
    fape_reduce<<<B, 256, 0, stream>>>(partial, out, nPart, N);
}